// Round 19
// baseline (171.190 us; speedup 1.0000x reference)
//
#include <hip/hip_runtime.h>
#include <hip/hip_bf16.h>
#include <cstdint>
#include <cstddef>

// ---------- types ----------
using u16 = unsigned short;
typedef __attribute__((ext_vector_type(4))) float f32x4;
typedef __attribute__((ext_vector_type(16))) float f32x16;
typedef __attribute__((ext_vector_type(8))) unsigned short u16x8;
typedef __attribute__((ext_vector_type(4))) unsigned short u16x4;
typedef __attribute__((ext_vector_type(2))) unsigned short u16x2;
typedef __attribute__((ext_vector_type(4))) unsigned int u32x4;
typedef __bf16 bfrag __attribute__((ext_vector_type(8)));   // 8 bf16 = 4 VGPR MFMA operand

constexpr int Hn = 8, Cn = 1024, Dn = 128, Fn = 512, Bn = 16;
constexpr int M1 = Bn * Cn;  // 16384 rows of x / att_out

// workspace layout (bytes)
constexpr size_t OFF_XB  = 0;                                  // x bf16 [16384][512]
constexpr size_t SZ_XB   = (size_t)M1 * Fn * 2;                // 16 MiB
constexpr size_t OFF_WT  = OFF_XB + SZ_XB;                     // Wt bf16 [3][1024][512] (q,k,v)
constexpr size_t SZ_WT   = 3ull * 1024 * 512 * 2;              // 3 MiB
constexpr size_t OFF_W0T = OFF_WT + SZ_WT;                     // Ww0^T bf16 [128][1024]
constexpr size_t SZ_W0T  = 128ull * 1024 * 2;
constexpr size_t OFF_Q   = OFF_W0T + SZ_W0T;                   // q perm [16][8][1024][128] bf16
constexpr size_t SZ_P    = (size_t)Bn * Hn * Cn * Dn * 2;      // 32 MiB each
constexpr size_t OFF_K   = OFF_Q + SZ_P;                       // Kt2: [bh][y][128 k][128 d], c'=8k+y
constexpr size_t OFF_V   = OFF_K + SZ_P;                       // Vt2: [bh][y][128 d][128 k], c'=8k+y
constexpr size_t OFF_ATT = OFF_V + SZ_P;                       // vals2 bf16 [16384][1024]

// ---------- helpers ----------
__device__ __forceinline__ float bf2f(u16 u) {
  unsigned int x = ((unsigned int)u) << 16;
  return __builtin_bit_cast(float, x);
}
__device__ __forceinline__ u16 f2bf(float f) {
  unsigned int u = __builtin_bit_cast(unsigned int, f);
  u += 0x7fffu + ((u >> 16) & 1u);   // RNE
  return (u16)(u >> 16);
}
__device__ __forceinline__ f32x4 mfma16(bfrag a, bfrag b, f32x4 c) {
  return __builtin_amdgcn_mfma_f32_16x16x32_bf16(a, b, c, 0, 0, 0);
}
__device__ __forceinline__ f32x16 mfma32(bfrag a, bfrag b, f32x16 c) {
  return __builtin_amdgcn_mfma_f32_32x32x16_bf16(a, b, c, 0, 0, 0);
}
// async 16B global->LDS; lds base must be wave-uniform (lane*16 auto-offset)
__device__ __forceinline__ void gload16(const void* g, void* lds) {
  __builtin_amdgcn_global_load_lds(
      (const __attribute__((address_space(1))) unsigned int*)g,
      (__attribute__((address_space(3))) unsigned int*)lds, 16, 0, 0);
}
__device__ __forceinline__ unsigned cvtpk(float lo, float hi) {
  unsigned r;
  asm("v_cvt_pk_bf16_f32 %0, %1, %2" : "=v"(r) : "v"(lo), "v"(hi));
  return r;
}
// raw HW exp2 (1 instr; valid here: |x| < ~2 by construction)
__device__ __forceinline__ float fexp2(float x) {
  float r;
  asm("v_exp_f32 %0, %1" : "=v"(r) : "v"(x));
  return r;
}

// ---------- prep kernels ----------
// 8 elems/thread: 2 x float4 in, 1 x u16x8 out
__global__ void cvt_bf16(const float* __restrict__ in, u16* __restrict__ out, int n) {
  int idx = (blockIdx.x * blockDim.x + threadIdx.x) * 8;
  if (idx < n) {
    float4 v0 = *(const float4*)(in + idx);
    float4 v1 = *(const float4*)(in + idx + 4);
    u16x8 o;
    o[0] = f2bf(v0.x); o[1] = f2bf(v0.y); o[2] = f2bf(v0.z); o[3] = f2bf(v0.w);
    o[4] = f2bf(v1.x); o[5] = f2bf(v1.y); o[6] = f2bf(v1.z); o[7] = f2bf(v1.w);
    *(u16x8*)(out + idx) = o;
  }
}

// in [R][Cc] f32 -> out [Cc][R] bf16 ; block (32,8), grid (Cc/32, R/32)
__global__ void transpose_cvt(const float* __restrict__ in, u16* __restrict__ out,
                              int R, int Cc) {
  __shared__ float tile[32][33];
  int c0 = blockIdx.x * 32, r0 = blockIdx.y * 32;
  int tx = threadIdx.x, ty = threadIdx.y;
#pragma unroll
  for (int i = 0; i < 4; ++i)
    tile[ty + i * 8][tx] = in[(size_t)(r0 + ty + i * 8) * Cc + c0 + tx];
  __syncthreads();
#pragma unroll
  for (int i = 0; i < 4; ++i)
    out[(size_t)(c0 + ty + i * 8) * R + r0 + tx] = f2bf(tile[tx][ty + i * 8]);
}

// fused: the three 512x1024 weight transposes in one launch (z = which matrix)
__global__ void transpose_cvt3(const float* __restrict__ W0, const float* __restrict__ W1,
                               const float* __restrict__ W2, u16* __restrict__ out) {
  __shared__ float tile[32][33];
  const int z = blockIdx.z;
  const float* in = (z == 0) ? W0 : (z == 1) ? W1 : W2;
  u16* op = out + (size_t)z * 1024 * 512;
  int c0 = blockIdx.x * 32, r0 = blockIdx.y * 32;
  int tx = threadIdx.x, ty = threadIdx.y;
#pragma unroll
  for (int i = 0; i < 4; ++i)
    tile[ty + i * 8][tx] = in[(size_t)(r0 + ty + i * 8) * 1024 + c0 + tx];
  __syncthreads();
#pragma unroll
  for (int i = 0; i < 4; ++i)
    op[(size_t)(c0 + ty + i * 8) * 512 + r0 + tx] = f2bf(tile[tx][ty + i * 8]);
}

// ---------- QKV projection GEMM (R12 structure; K->Kt2, V->Vt2 layouts) ----------
// Q output in perm layout [bh][c'][d], pre-scaled by log2(e)/sqrt(D).
// K (p==1): Kt2[bh][y][k][d] with c'=8k+y (k=c&127, y=j>>7) -- same 32B/16-lane
// store coalescing as the perm write, but attn can stage tile (y,kb) as ONE
// contiguous 16KB block.
// V (p==2): block y computes the FULL [d][k] plane of Vt2[bh][y]; epilogue
// transposes acc through the 32KB LDS and writes coalesced u16x8 rows.
__global__ void qkv_gemm(const u16* __restrict__ xb, const u16* __restrict__ wt,
                         const float* __restrict__ bq, const float* __restrict__ bk,
                         const float* __restrict__ bv,
                         u16* __restrict__ qout, u16* __restrict__ kout,
                         u16* __restrict__ vout) {
  __shared__ u16 sAB[16384];   // As 8192 u16 | Bs 8192 u16 ; reused as 128x128 tile
  u16* As = sAB;
  u16* Bs = sAB + 8192;
  const int m0 = blockIdx.x * 128;
  const int n0 = blockIdx.y * 128;
  const int p  = blockIdx.z;
  const u16* wp = wt + (size_t)p * 1024 * 512;
  const float* bias = (p == 0) ? bq : (p == 1) ? bk : bv;
  const float osc = (p == 0) ? 0.12751744116389548f : 1.0f;  // log2(e)/sqrt(128)

  const int tid = threadIdx.x, l = tid & 63, w = tid >> 6;
  const int lr = l & 15, lg = l >> 4;
  const int wr = w >> 1, wc = w & 1;

  f32x4 acc[4][4] = {};

  for (int kt = 0; kt < Fn; kt += 64) {
#pragma unroll
    for (int i = 0; i < 4; ++i) {
      int chb = (i * 4 + w) * 64;
      int ch = chb + l;
      int row = ch >> 3, scc = (ch & 7) ^ (row & 7);
      gload16(xb + (size_t)(m0 + row) * Fn + kt + scc * 8, &As[chb * 8]);
    }
#pragma unroll
    for (int i = 0; i < 4; ++i) {
      int chb = (i * 4 + w) * 64;
      int ch = chb + l;
      int row = ch >> 3, scc = (ch & 7) ^ (row & 7);
      gload16(wp + (size_t)(n0 + row) * Fn + kt + scc * 8, &Bs[chb * 8]);
    }
    __syncthreads();
#pragma unroll
    for (int kk = 0; kk < 2; ++kk) {
      bfrag af[4], bf_[4];
#pragma unroll
      for (int fm = 0; fm < 4; ++fm) {
        int row = wr * 64 + fm * 16 + lr;
        int off = (kk * 4 + lg) ^ (row & 7);
        af[fm] = *(const bfrag*)&As[row * 64 + off * 8];
      }
#pragma unroll
      for (int fn = 0; fn < 4; ++fn) {
        int row = wc * 64 + fn * 16 + lr;
        int off = (kk * 4 + lg) ^ (row & 7);
        bf_[fn] = *(const bfrag*)&Bs[row * 64 + off * 8];
      }
#pragma unroll
      for (int fm = 0; fm < 4; ++fm)
#pragma unroll
        for (int fn = 0; fn < 4; ++fn)
          acc[fm][fn] = mfma16(af[fm], bf_[fn], acc[fm][fn]);
    }
    __syncthreads();
  }

  if (p == 2) {
    // ---- V epilogue: acc -> LDS transpose -> Vt2[bh][y][d][k] coalesced ----
    const int y = n0 >> 7;
#pragma unroll
    for (int fm = 0; fm < 4; ++fm) {
#pragma unroll
      for (int fn = 0; fn < 4; ++fn) {
        int kb = wr * 64 + fm * 16 + lg * 4;       // k base (multiple of 4)
        int d  = wc * 64 + fn * 16 + lr;
        float b0 = bias[n0 + d];
        unsigned p01 = cvtpk(acc[fm][fn][0] + b0, acc[fm][fn][1] + b0);
        unsigned p23 = cvtpk(acc[fm][fn][2] + b0, acc[fm][fn][3] + b0);
        int kx = kb ^ ((d & 7) << 3);              // XOR bits 3-5: pairs stay contiguous
        *(unsigned*)&sAB[d * 128 + kx]     = p01;
        *(unsigned*)&sAB[d * 128 + kx + 2] = p23;
      }
    }
    __syncthreads();
    const int b = m0 >> 10, gh = (m0 & 1023) >> 7;
    u16* outv = vout + ((size_t)((b * 8 + gh) * 8 + y)) * 16384;
#pragma unroll
    for (int i = 0; i < 8; ++i) {
      int g = i * 256 + tid;
      int d = g >> 4, s = g & 15;
      u16x8 vv = *(const u16x8*)&sAB[d * 128 + ((s ^ (d & 7)) << 3)];
      *(u16x8*)&outv[d * 128 + s * 8] = vv;
    }
    return;
  }

  // ---- Q/K epilogue ----
  u16* outp = (p == 0) ? qout : kout;
#pragma unroll
  for (int fm = 0; fm < 4; ++fm) {
#pragma unroll
    for (int r = 0; r < 4; ++r) {
      int m = m0 + wr * 64 + fm * 16 + lg * 4 + r;
      int b = m >> 10, c = m & 1023;
      int gh = c >> 7;
#pragma unroll
      for (int fn = 0; fn < 4; ++fn) {
        int j = n0 + wc * 64 + fn * 16 + lr;
        float v = (acc[fm][fn][r] + bias[j]) * osc;
        int d = j & 127;
        size_t idx;
        if (p == 1) {
          // Kt2: [bh][y=j>>7][k=c&127][d]
          idx = ((size_t)((b * 8 + gh) * 8 + (j >> 7))) * 16384 + (size_t)(c & 127) * 128 + d;
        } else {
          // Q perm: [bh][c'=(c&127)*8+(j>>7)][d]
          int ii = ((c & 127) << 3) | (j >> 7);
          idx = (((size_t)(b * 8 + gh) * 1024 + ii) << 7) | d;
        }
        outp[idx] = f2bf(v);
      }
    }
  }
}

// ---------- fused flash attention (8-wave block, no-max softmax, y-major kv tiles) ----------
// O = softmax(QK^T/sqrt(D))@V - V.  512 blocks (XCD-swizzled) x 512 threads;
// S^T = mfma32(K,Q); P = exp2(S') directly (bounded domain); in-register P^T
// via cvt_pk + permlane32_swap; O^T = mfma32(V^T,P^T); XOR-folded addressing.
// kv tiles iterate (y, kb): tile t = y*2+kb covers channels c' = 8k+y,
// k in [64kb, 64kb+64).  BOTH K and V now stage from contiguous blocks:
// K from Kt2[y][64kb..64kb+64)[.] (one 16KB block), V rows from
// Vt2[y][d][64kb..64kb+64] (contiguous 128B per 8 lanes).  kv order is a
// global permutation -- no-max softmax + order-independent lsum make it free.
// P/V slot consistency: V slot s entry e = k=64kb+8s+e = K row j=8s+e.
__global__ __launch_bounds__(512, 2)
void attn_kernel(const u16* __restrict__ qp_all, const u16* __restrict__ kt_all,
                 const u16* __restrict__ vt_all, u16* __restrict__ attout) {
  __shared__ u16 smem[2 * 16384];
  char* smb = (char*)smem;

  const int bid = blockIdx.x;
  const int wg = (bid & 7) * 64 + (bid >> 3);
  const int bh = wg >> 2;
  const int qtp = wg & 3;

  const int tid = threadIdx.x, l = tid & 63, w = tid >> 6;   // w in 0..7
  const int q31 = l & 31, hi = l >> 5;

  const u16* qp  = qp_all + (size_t)bh * (Cn * Dn);
  const u16* ktp = kt_all + (size_t)bh * (Cn * Dn);   // Kt2[bh]: [y][k][d]
  const u16* vtp = vt_all + (size_t)bh * (Dn * Cn);   // Vt2[bh]: [y][d][k]
  const int qr0 = qtp * 256 + w * 32;    // wave's 32 q-rows within the head

  const unsigned LK = (unsigned)(q31 * 256) ^ (unsigned)((q31 & 15) * 16) ^ (unsigned)(hi * 16);
  const unsigned LV = 16384u ^ (unsigned)(q31 * 128) ^ (unsigned)((q31 & 7) * 16) ^ (unsigned)(hi * 16);

  const u16* ksrc[2]; const u16* vsrc[2];
  unsigned kdst[2], vdst[2];
#pragma unroll
  for (int c = 0; c < 2; ++c) {
    int ch = c * 512 + tid;
    // K: dest row j holds k = 64kb + j -> contiguous rows of Kt2[y] plane
    int krow = ch >> 4, kscc = (ch & 15) ^ (krow & 15);
    ksrc[c] = ktp + (size_t)krow * 128 + kscc * 8;
    // V: dest (row d, phys slot) -> logical slot s; source Vt2[y][d][64kb+8s]
    int vrow = ch >> 3;
    int vslog = (ch & 7) ^ (vrow & 7);
    vsrc[c] = vtp + (size_t)vrow * 128 + vslog * 8;
    kdst[c] = (unsigned)((c * 512 + w * 64) * 16);
    vdst[c] = 16384u + (unsigned)((c * 512 + w * 64) * 16);
  }
  auto stage = [&](int t2, unsigned bufb) {
    const int y = t2 >> 1, kb = t2 & 1;
    const size_t koff = (size_t)y * 16384 + (size_t)kb * 8192;  // elems
    const size_t voff = (size_t)y * 16384 + (size_t)kb * 64;    // elems
#pragma unroll
    for (int c = 0; c < 2; ++c)
      gload16(ksrc[c] + koff, smb + (bufb ^ kdst[c]));
#pragma unroll
    for (int c = 0; c < 2; ++c)
      gload16(vsrc[c] + voff, smb + (bufb ^ vdst[c]));
  };

  bfrag aq[8];
#pragma unroll
  for (int kk = 0; kk < 8; ++kk)
    aq[kk] = *(const bfrag*)(qp + (size_t)(qr0 + q31) * Dn + kk * 16 + hi * 8);

  f32x16 ot[4] = {};                 // O^T accumulator: col q=q31, rows d
  float lsum = 0.f;                  // per-lane HALF-sum of exp2 (combined at end)

  stage(0, 0);
  __syncthreads();

  unsigned bufb = 0;
  for (int t = 0; t < 16; ++t) {
    const unsigned nb = bufb ^ 32768u;
    if (t < 15) stage(t + 1, nb);    // lands during this iter's compute
    const unsigned LKb = LK ^ bufb;
    const unsigned LVb = LV ^ bufb;

    f32x16 st0 = {}, st1 = {};
    __builtin_amdgcn_s_setprio(1);
#pragma unroll
    for (int kk = 0; kk < 8; ++kk) {
      bfrag k0 = *(const bfrag*)(smb + (LKb ^ (unsigned)(kk * 32)));
      st0 = mfma32(k0, aq[kk], st0);
      bfrag k1 = *(const bfrag*)(smb + (LKb ^ (unsigned)(8192 + kk * 32)));
      st1 = mfma32(k1, aq[kk], st1);
    }
    __builtin_amdgcn_s_setprio(0);

    float rp[4] = {0.f, 0.f, 0.f, 0.f};
#pragma unroll
    for (int r = 0; r < 16; ++r) {
      float p0 = fexp2(st0[r]);
      st0[r] = p0;
      rp[r & 3] += p0;
    }
#pragma unroll
    for (int r = 0; r < 16; ++r) {
      float p1 = fexp2(st1[r]);
      st1[r] = p1;
      rp[r & 3] += p1;
    }
    lsum += (rp[0] + rp[1]) + (rp[2] + rp[3]);

    bfrag pb[4];
    {
      unsigned c0_[8], c1_[8];
#pragma unroll
      for (int m = 0; m < 8; ++m) {
        c0_[m] = cvtpk(st0[2 * m], st0[2 * m + 1]);
        c1_[m] = cvtpk(st1[2 * m], st1[2 * m + 1]);
      }
#pragma unroll
      for (int kkt = 0; kkt < 2; ++kkt) {
        unsigned a0 = c0_[4 * kkt + 0], b0 = c0_[4 * kkt + 2];
        unsigned a1 = c0_[4 * kkt + 1], b1 = c0_[4 * kkt + 3];
        asm("v_permlane32_swap_b32 %0, %1" : "+v"(a0), "+v"(b0));
        asm("v_permlane32_swap_b32 %0, %1" : "+v"(a1), "+v"(b1));
        u32x4 bw; bw.x = a0; bw.y = a1; bw.z = b0; bw.w = b1;
        pb[kkt] = __builtin_bit_cast(bfrag, bw);
      }
#pragma unroll
      for (int kkt = 0; kkt < 2; ++kkt) {
        unsigned a0 = c1_[4 * kkt + 0], b0 = c1_[4 * kkt + 2];
        unsigned a1 = c1_[4 * kkt + 1], b1 = c1_[4 * kkt + 3];
        asm("v_permlane32_swap_b32 %0, %1" : "+v"(a0), "+v"(b0));
        asm("v_permlane32_swap_b32 %0, %1" : "+v"(a1), "+v"(b1));
        u32x4 bw; bw.x = a0; bw.y = a1; bw.z = b0; bw.w = b1;
        pb[2 + kkt] = __builtin_bit_cast(bfrag, bw);
      }
    }

    __builtin_amdgcn_s_setprio(1);
#pragma unroll
    for (int kk = 0; kk < 4; ++kk) {
#pragma unroll
      for (int dt = 0; dt < 4; ++dt) {
        bfrag vf = *(const bfrag*)(smb + (LVb ^ (unsigned)(dt * 4096 + kk * 32)));
        ot[dt] = mfma32(vf, pb[kk], ot[dt]);
      }
    }
    __builtin_amdgcn_s_setprio(0);
    __syncthreads();  // drains vmcnt(0): prefetch (issued at iter top) landed
    bufb = nb;
  }

  // ---- epilogue: combine half-sums, (O^T/l - V(d,c1)) -> LDS -> write ----
  const float lfull = lsum + __shfl_xor(lsum, 32, 64);
  const float linv = 1.f / lfull;
  const int c1 = qr0 + q31;
  const u16* vcol = vtp + (size_t)(c1 & 7) * 16384 + (c1 >> 3);  // Vt2[y=c1&7][.][k=c1>>3]
  u16* my = smem + w * 4096;
#pragma unroll
  for (int dt = 0; dt < 4; ++dt)
#pragma unroll
    for (int rp2 = 0; rp2 < 8; ++rp2) {
      int reg = 2 * rp2;
      int d = dt * 32 + (reg & 3) + 8 * (reg >> 2) + 4 * hi;
      float v0 = bf2f(vcol[(size_t)d * 128]);
      float v1 = bf2f(vcol[(size_t)(d + 1) * 128]);
      unsigned pk = cvtpk(ot[dt][reg] * linv - v0, ot[dt][reg + 1] * linv - v1);
      *(unsigned*)&my[q31 * 128 + (((d >> 3) ^ (q31 & 7)) << 3) + (d & 7)] = pk;
    }
  const int b = bh >> 3, h = bh & 7;
#pragma unroll
  for (int it = 0; it < 8; ++it) {
    int rowq = it * 4 + (l >> 4);
    int ch = l & 15;
    u16x8 rd = *(const u16x8*)&my[rowq * 128 + ((ch ^ (rowq & 7))) * 8];
    int cg = qr0 + rowq;
    *(u16x8*)&attout[(((size_t)(b * 1024 + cg)) * 8 + h) * 128 + ch * 8] = rd;
  }
}

// ---------- output GEMM: [16384][1024] @ [1024][128] + bias -> f32 ----------
__global__ void out_gemm(const u16* __restrict__ A, const u16* __restrict__ Bt,
                         const float* __restrict__ bias, float* __restrict__ out) {
  __shared__ u16 As[32 * 64];
  __shared__ u16 Bs[128 * 64];
  const int m0 = blockIdx.x * 32;
  const int tid = threadIdx.x, l = tid & 63, w = tid >> 6;
  const int lr = l & 15, lg = l >> 4;
  f32x4 acc[2][2] = {};

  for (int kt = 0; kt < 1024; kt += 64) {
    {   // As: 256 chunks, 1/thread
      int ch = w * 64 + l;
      int row = ch >> 3, scc = (ch & 7) ^ (row & 7);
      gload16(A + (size_t)(m0 + row) * 1024 + kt + scc * 8, &As[(w * 64) * 8]);
    }
#pragma unroll
    for (int i = 0; i < 4; ++i) {   // Bs: 1024 chunks, 4/thread
      int chb = (i * 4 + w) * 64;
      int ch = chb + l;
      int row = ch >> 3, scc = (ch & 7) ^ (row & 7);
      gload16(Bt + (size_t)row * 1024 + kt + scc * 8, &Bs[chb * 8]);
    }
    __syncthreads();
#pragma unroll
    for (int kk = 0; kk < 2; ++kk) {
      bfrag af[2], bf_[2];
#pragma unroll
      for (int fm = 0; fm < 2; ++fm) {
        int row = fm * 16 + lr;
        int off = (kk * 4 + lg) ^ (row & 7);
        af[fm] = *(const bfrag*)&As[row * 64 + off * 8];
      }
#pragma unroll
      for (int fn = 0; fn < 2; ++fn) {
        int row = w * 32 + fn * 16 + lr;
        int off = (kk * 4 + lg) ^ (row & 7);
        bf_[fn] = *(const bfrag*)&Bs[row * 64 + off * 8];
      }
#pragma unroll
      for (int fm = 0; fm < 2; ++fm)
#pragma unroll
        for (int fn = 0; fn < 2; ++fn)
          acc[fm][fn] = mfma16(af[fm], bf_[fn], acc[fm][fn]);
    }
    __syncthreads();
  }
#pragma unroll
  for (int fm = 0; fm < 2; ++fm)
#pragma unroll
    for (int r = 0; r < 4; ++r) {
      int m = m0 + fm * 16 + lg * 4 + r;
#pragma unroll
      for (int fn = 0; fn < 2; ++fn) {
        int j = w * 32 + fn * 16 + lr;
        out[(size_t)m * 128 + j] = acc[fm][fn][r] + bias[j];
      }
    }
}

// ---------- launch ----------
extern "C" void kernel_launch(void* const* d_in, const int* in_sizes, int n_in,
                              void* d_out, int out_size, void* d_ws, size_t ws_size,
                              hipStream_t stream) {
  const float* x   = (const float*)d_in[0];
  const float* Wk  = (const float*)d_in[1];
  const float* bk_ = (const float*)d_in[2];
  const float* Wq  = (const float*)d_in[3];
  const float* bq_ = (const float*)d_in[4];
  const float* Wv  = (const float*)d_in[5];
  const float* bv_ = (const float*)d_in[6];
  const float* Ww0 = (const float*)d_in[7];
  const float* bw0 = (const float*)d_in[8];
  float* out = (float*)d_out;

  char* ws = (char*)d_ws;
  u16* xb   = (u16*)(ws + OFF_XB);
  u16* wt   = (u16*)(ws + OFF_WT);
  u16* w0t  = (u16*)(ws + OFF_W0T);
  u16* qpm  = (u16*)(ws + OFF_Q);
  u16* kpm  = (u16*)(ws + OFF_K);   // Kt2 layout
  u16* vpm  = (u16*)(ws + OFF_V);   // Vt2 layout
  u16* attb = (u16*)(ws + OFF_ATT); // attn output

  // prep: cast x (8/thread), transpose+cast weights (3 fused + w0)
  cvt_bf16<<<(M1 * Fn / 8 + 255) / 256, 256, 0, stream>>>(x, xb, M1 * Fn);
  dim3 tb(32, 8);
  transpose_cvt3<<<dim3(32, 16, 3), tb, 0, stream>>>(Wq, Wk, Wv, wt);
  transpose_cvt<<<dim3(4, 32), tb, 0, stream>>>(Ww0, w0t, 1024, 128);

  // projections: Q -> perm, K -> Kt2, V -> Vt2
  qkv_gemm<<<dim3(128, 8, 3), 256, 0, stream>>>(xb, wt, bq_, bk_, bv_, qpm, kpm, vpm);

  // fused attention (softmax - I folded as O = P@V - V), y-major kv tiles
  attn_kernel<<<dim3(512), 512, 0, stream>>>(qpm, kpm, vpm, attb);

  // output projection (f32 out + bias)
  out_gemm<<<512, 256, 0, stream>>>(attb, w0t, bw0, out);
}